// Round 1
// baseline (81415.448 us; speedup 1.0000x reference)
//
#include <hip/hip_runtime.h>

#define B_ 64
#define T_ 512
#define D_ 256
#define H_ 256
#define G3_ 768   // 3*H
#define L_ 5

// ---------------------------------------------------------------------------
// Embedding gather: x[row][d] = emb[tokens[row]][d], row in [0, B*T)
// ---------------------------------------------------------------------------
__global__ void embed_kernel(const int* __restrict__ tokens,
                             const float* __restrict__ emb,
                             float* __restrict__ x) {
  int row  = blockIdx.x * 4 + (threadIdx.x >> 6);
  int lane = threadIdx.x & 63;
  int tok  = tokens[row];
  const float4* src = (const float4*)(emb + (size_t)tok * D_);
  float4*       dst = (float4*)(x + (size_t)row * D_);
  dst[lane] = src[lane];
}

// ---------------------------------------------------------------------------
// xproj GEMM: C[M=32768][768] = X[M][256] @ W[256][768] + bi
// f32 tiled (no fp32 MFMA on CDNA4). 64x64 tile, BK=16, 256 threads, 4x4/thread.
// ---------------------------------------------------------------------------
__global__ __launch_bounds__(256) void gemm_xproj(
    const float* __restrict__ X,
    const float* __restrict__ W,
    const float* __restrict__ bi,
    float* __restrict__ C) {
  __shared__ float As[16][68];   // [k][m], padded (68*4=272B = 17*16, float4-aligned)
  __shared__ float Bs[16][64];   // [k][n]
  const int tid = threadIdx.x;
  const int tx = tid & 15, ty = tid >> 4;
  const int m0 = blockIdx.y * 64;
  const int n0 = blockIdx.x * 64;
  const int lr = tid >> 2, lseg = tid & 3;    // X loader: row, k-segment
  const int wk = tid >> 4, wseg = tid & 15;   // W loader: k-row, n-segment

  float acc[4][4] = {};
  for (int k0 = 0; k0 < 256; k0 += 16) {
    float4 xv = *(const float4*)(X + (size_t)(m0 + lr) * D_ + k0 + lseg * 4);
    As[lseg * 4 + 0][lr] = xv.x;
    As[lseg * 4 + 1][lr] = xv.y;
    As[lseg * 4 + 2][lr] = xv.z;
    As[lseg * 4 + 3][lr] = xv.w;
    *(float4*)&Bs[wk][wseg * 4] =
        *(const float4*)(W + (size_t)(k0 + wk) * G3_ + n0 + wseg * 4);
    __syncthreads();
#pragma unroll
    for (int k = 0; k < 16; ++k) {
      float a[4], b[4];
      *(float4*)a = *(const float4*)&As[k][ty * 4];
      *(float4*)b = *(const float4*)&Bs[k][tx * 4];
#pragma unroll
      for (int q = 0; q < 4; ++q)
#pragma unroll
        for (int i = 0; i < 4; ++i) acc[q][i] += a[q] * b[i];
    }
    __syncthreads();
  }
  float4 bv = *(const float4*)(bi + n0 + tx * 4);
#pragma unroll
  for (int q = 0; q < 4; ++q) {
    float4 o;
    o.x = acc[q][0] + bv.x;
    o.y = acc[q][1] + bv.y;
    o.z = acc[q][2] + bv.z;
    o.w = acc[q][3] + bv.w;
    *(float4*)(C + (size_t)(m0 + ty * 4 + q) * G3_ + n0 + tx * 4) = o;
  }
}

// ---------------------------------------------------------------------------
// Persistent GRU scan. Grid = 512 WGs = 64 batches x 8 slices. Block = 384.
// Thread t: column c = t>>2 (0..95), k-segment ks = t&3.
// Column c -> gate g = c>>5 (z,r,h), j = c&31, global col n = g*256 + s*32 + j.
// R column segment (64 values) held in VGPRs. h double-buffered in global,
// per-batch arrival counter with agent-scope release/acquire.
// ---------------------------------------------------------------------------
template <bool RETURN_SEQ>
__global__ __launch_bounds__(384, 3) void scan_kernel(
    const float* __restrict__ xproj,   // [B][T][768]
    const float* __restrict__ Rl,      // [256][768]
    const float* __restrict__ brl,     // [768]
    const int* __restrict__ tokens,    // [B][T]
    float* __restrict__ y,             // [B][T][256] (if RETURN_SEQ)
    float* hbuf,                       // [2][B][256], zeroed
    unsigned int* cnt) {               // [B], zeroed
  const int b   = blockIdx.x >> 3;
  const int s   = blockIdx.x & 7;
  const int tid = threadIdx.x;
  const int c   = tid >> 2;
  const int ks  = tid & 3;
  const int g   = c >> 5;
  const int j   = c & 31;
  const int n   = g * 256 + s * 32 + j;

  __shared__ float h_lds[4 * 72];   // 4 segments of 64, stride 72 (bank-shifted, 16B-aligned)
  __shared__ float recbuf[96];

  // Load this thread's R column segment into registers (one-time, L2-served).
  float Rreg[64];
#pragma unroll
  for (int i = 0; i < 64; ++i) Rreg[i] = Rl[(size_t)(ks * 64 + i) * G3_ + n];
  const float br = brl[n];

  for (int t = 0; t < T_; ++t) {
    if (t > 0) {
      if (tid == 0) {
        while (__hip_atomic_load(cnt + b, __ATOMIC_ACQUIRE,
                                 __HIP_MEMORY_SCOPE_AGENT) < (unsigned)(8 * t)) {
        }
      }
      __syncthreads();
    }
    const float* hsrc = hbuf + (size_t)(t & 1) * B_ * H_ + b * H_;
    if (tid < 256) {
      float hv = __hip_atomic_load(hsrc + tid, __ATOMIC_RELAXED,
                                   __HIP_MEMORY_SCOPE_AGENT);
      h_lds[(tid >> 6) * 72 + (tid & 63)] = hv;
    }
    float xz, xr, xh;
    int tok = 0;
    if (tid < 32) {  // prefetch gate inputs while dot product runs
      const float* xp = xproj + ((size_t)b * T_ + t) * G3_ + s * 32 + tid;
      xz = xp[0];
      xr = xp[256];
      xh = xp[512];
      tok = tokens[b * T_ + t];
    }
    __syncthreads();

    float a = 0.f;
    const float* hseg = &h_lds[ks * 72];
#pragma unroll
    for (int i = 0; i < 16; ++i) {
      float4 hv = *(const float4*)(hseg + 4 * i);
      a += Rreg[4 * i + 0] * hv.x;
      a += Rreg[4 * i + 1] * hv.y;
      a += Rreg[4 * i + 2] * hv.z;
      a += Rreg[4 * i + 3] * hv.w;
    }
    a += __shfl_xor(a, 1);
    a += __shfl_xor(a, 2);
    if (ks == 0) recbuf[c] = a + br;
    __syncthreads();

    if (tid < 32) {
      float rz = recbuf[tid], rr = recbuf[32 + tid], rh = recbuf[64 + tid];
      float z  = 1.f / (1.f + expf(-(xz + rz)));
      float r  = 1.f / (1.f + expf(-(xr + rr)));
      float hh = tanhf(xh + r * rh);
      int hidx = s * 32 + tid;
      float hold = h_lds[(hidx >> 6) * 72 + (hidx & 63)];
      float hnew = z * hold + (1.f - z) * hh;
      float hval = (tok != 0) ? hnew : hold;
      __hip_atomic_store(hbuf + (size_t)((t + 1) & 1) * B_ * H_ + b * H_ + hidx,
                         hval, __ATOMIC_RELAXED, __HIP_MEMORY_SCOPE_AGENT);
      if (RETURN_SEQ) y[((size_t)b * T_ + t) * H_ + hidx] = hval;
    }
    __syncthreads();
    if (tid == 0) {
      __threadfence();
      __hip_atomic_fetch_add(cnt + b, 1u, __ATOMIC_RELEASE,
                             __HIP_MEMORY_SCOPE_AGENT);
    }
  }
}

// ---------------------------------------------------------------------------
// Final FC: out[b][c] = h[b] . fcW[:,c] + fcb[c]   (64x10, trivial)
// ---------------------------------------------------------------------------
__global__ void fc_kernel(const float* __restrict__ h,   // hbuf[0]: [B][256]
                          const float* __restrict__ fcW, // [256][10]
                          const float* __restrict__ fcb,
                          float* __restrict__ out) {
  int b = blockIdx.x;
  int c = threadIdx.x;
  if (c < 10) {
    float s = fcb[c];
    for (int k = 0; k < H_; ++k) s += h[b * H_ + k] * fcW[k * 10 + c];
    out[b * 10 + c] = s;
  }
}

// ---------------------------------------------------------------------------
extern "C" void kernel_launch(void* const* d_in, const int* in_sizes, int n_in,
                              void* d_out, int out_size, void* d_ws,
                              size_t ws_size, hipStream_t stream) {
  const int*   tokens = (const int*)d_in[0];
  const float* emb    = (const float*)d_in[1];
  const float* W      = (const float*)d_in[2];   // [5][256][768]
  const float* Rw     = (const float*)d_in[3];   // [5][256][768]
  const float* bi     = (const float*)d_in[4];   // [5][768]
  const float* br     = (const float*)d_in[5];   // [5][768]
  const float* fcW    = (const float*)d_in[6];   // [256][10]
  const float* fcb    = (const float*)d_in[7];   // [10]
  float*       out    = (float*)d_out;

  char* ws = (char*)d_ws;
  const size_t SEQ_BYTES = (size_t)B_ * T_ * D_ * 4;       // 33.5 MB
  float* x_buf  = (float*)(ws);
  float* y_buf  = (float*)(ws + SEQ_BYTES);
  float* xproj  = (float*)(ws + 2 * SEQ_BYTES);            // 100.7 MB
  float* hbuf   = (float*)(ws + 2 * SEQ_BYTES + (size_t)B_ * T_ * G3_ * 4);
  unsigned int* cnt = (unsigned int*)((char*)hbuf + 2 * B_ * H_ * 4);

  embed_kernel<<<(B_ * T_) / 4, 256, 0, stream>>>(tokens, emb, x_buf);

  const float* in_seq = x_buf;
  float*       out_seq = y_buf;
  for (int l = 0; l < L_; ++l) {
    gemm_xproj<<<dim3(G3_ / 64, (B_ * T_) / 64), 256, 0, stream>>>(
        in_seq, W + (size_t)l * D_ * G3_, bi + (size_t)l * G3_, xproj);
    hipMemsetAsync(hbuf, 0, 2 * B_ * H_ * 4 + 1024, stream);
    if (l < L_ - 1) {
      scan_kernel<true><<<B_ * 8, 384, 0, stream>>>(
          xproj, Rw + (size_t)l * D_ * G3_, br + (size_t)l * G3_, tokens,
          out_seq, hbuf, cnt);
    } else {
      scan_kernel<false><<<B_ * 8, 384, 0, stream>>>(
          xproj, Rw + (size_t)l * D_ * G3_, br + (size_t)l * G3_, tokens,
          nullptr, hbuf, cnt);
    }
    const float* tmp = in_seq;
    in_seq = out_seq;
    out_seq = (float*)tmp;
  }
  // After 512 steps, final h is in hbuf buffer 0 (writes went to buf[(511+1)&1]).
  fc_kernel<<<B_, 64, 0, stream>>>(hbuf, fcW, fcb, out);
}

// Round 2
// 71236.835 us; speedup vs baseline: 1.1429x; 1.1429x over previous
//
#include <hip/hip_runtime.h>

#define B_ 64
#define T_ 512
#define D_ 256
#define H_ 256
#define G3_ 768   // 3*H
#define L_ 5

typedef unsigned long long u64;

// ---------------------------------------------------------------------------
// Embedding gather: x[row][d] = emb[tokens[row]][d], row in [0, B*T)
// ---------------------------------------------------------------------------
__global__ void embed_kernel(const int* __restrict__ tokens,
                             const float* __restrict__ emb,
                             float* __restrict__ x) {
  int row  = blockIdx.x * 4 + (threadIdx.x >> 6);
  int lane = threadIdx.x & 63;
  int tok  = tokens[row];
  const float4* src = (const float4*)(emb + (size_t)tok * D_);
  float4*       dst = (float4*)(x + (size_t)row * D_);
  dst[lane] = src[lane];
}

// ---------------------------------------------------------------------------
// xproj GEMM: C[M=32768][768] = X[M][256] @ W[256][768] + bi
// f32 tiled (no fp32 MFMA on CDNA4). 64x64 tile, BK=16, 256 threads, 4x4/thread.
// ---------------------------------------------------------------------------
__global__ __launch_bounds__(256) void gemm_xproj(
    const float* __restrict__ X,
    const float* __restrict__ W,
    const float* __restrict__ bi,
    float* __restrict__ C) {
  __shared__ float As[16][68];
  __shared__ float Bs[16][64];
  const int tid = threadIdx.x;
  const int tx = tid & 15, ty = tid >> 4;
  const int m0 = blockIdx.y * 64;
  const int n0 = blockIdx.x * 64;
  const int lr = tid >> 2, lseg = tid & 3;
  const int wk = tid >> 4, wseg = tid & 15;

  float acc[4][4] = {};
  for (int k0 = 0; k0 < 256; k0 += 16) {
    float4 xv = *(const float4*)(X + (size_t)(m0 + lr) * D_ + k0 + lseg * 4);
    As[lseg * 4 + 0][lr] = xv.x;
    As[lseg * 4 + 1][lr] = xv.y;
    As[lseg * 4 + 2][lr] = xv.z;
    As[lseg * 4 + 3][lr] = xv.w;
    *(float4*)&Bs[wk][wseg * 4] =
        *(const float4*)(W + (size_t)(k0 + wk) * G3_ + n0 + wseg * 4);
    __syncthreads();
#pragma unroll
    for (int k = 0; k < 16; ++k) {
      float a[4], b[4];
      *(float4*)a = *(const float4*)&As[k][ty * 4];
      *(float4*)b = *(const float4*)&Bs[k][tx * 4];
#pragma unroll
      for (int q = 0; q < 4; ++q)
#pragma unroll
        for (int i = 0; i < 4; ++i) acc[q][i] += a[q] * b[i];
    }
    __syncthreads();
  }
  float4 bv = *(const float4*)(bi + n0 + tx * 4);
#pragma unroll
  for (int q = 0; q < 4; ++q) {
    float4 o;
    o.x = acc[q][0] + bv.x;
    o.y = acc[q][1] + bv.y;
    o.z = acc[q][2] + bv.z;
    o.w = acc[q][3] + bv.w;
    *(float4*)(C + (size_t)(m0 + ty * 4 + q) * G3_ + n0 + tx * 4) = o;
  }
}

// ---------------------------------------------------------------------------
// Persistent GRU scan, tag-in-data sync (no counters, no RMW, no fences).
//
// Grid = 256 WGs = 32 batch-pairs x 8 slice-WGs. Block = 768 threads.
// Thread t: j_local = t/24 (0..31), g = (t%24)/8 (z,r,h), seg = t%8.
// R column-segment (32 floats) in VGPRs, shared across the pair's 2 batches.
// h element = u64 atom: hi32 = step tag, lo32 = f32 value. Double-buffered
// by t-parity. Producers (gate lanes, tid<64) store (t+1, h) relaxed/agent;
// consumers poll tags of exactly the 32 words they need. Deadlock-safe:
// 256 WGs <= 256 CUs, each CU fits one 12-wave WG at <=168 VGPR.
// ---------------------------------------------------------------------------
template <bool RETURN_SEQ>
__global__ __launch_bounds__(768, 3) void scan_kernel(
    const float* __restrict__ xproj,   // [B][T][768]
    const float* __restrict__ Rl,      // [256][768]
    const float* __restrict__ brl,     // [768]
    const int* __restrict__ tokens,    // [B][T]
    float* __restrict__ y,             // [B][T][256] (if RETURN_SEQ)
    u64* hbuf) {                       // [2][B][256] packed (tag,value), zeroed
  const int blk   = blockIdx.x;
  const int bpair = blk >> 3;
  const int w     = blk & 7;
  const int tid   = threadIdx.x;
  const int j_local = tid / 24;
  const int rem     = tid - j_local * 24;
  const int g       = rem >> 3;
  const int seg     = rem & 7;
  const int n       = g * 256 + w * 32 + j_local;   // R column

  __shared__ float recbuf[2][2][32][3];   // [t&1][bsel][j][g]

  float Rreg[32];
#pragma unroll
  for (int i = 0; i < 32; ++i) Rreg[i] = Rl[(size_t)(seg * 32 + i) * G3_ + n];
  const float br = brl[n];

  // gate-lane identity (tid<64): bsel = tid>>5, j = tid&31
  const bool isGate = (tid < 64);
  const int  gb  = tid >> 5;
  const int  gj  = tid & 31;
  const int  gbb = bpair * 2 + gb;
  const int  gjg = w * 32 + gj;     // global h index this lane owns
  float hreg = 0.f;                 // owned h state, lives in a register

  for (int t = 0; t < T_; ++t) {
    // prefetch gate inputs (in flight during the polls below)
    float xz = 0.f, xr = 0.f, xh = 0.f;
    int tok = 0;
    if (isGate) {
      const float* xp = xproj + ((size_t)gbb * T_ + t) * G3_ + gjg;
      xz = xp[0];
      xr = xp[256];
      xh = xp[512];
      tok = tokens[gbb * T_ + t];
    }
    const unsigned tagt = (unsigned)t;

#pragma unroll
    for (int bsel = 0; bsel < 2; ++bsel) {
      const int bb = bpair * 2 + bsel;
      const u64* hp = hbuf + ((size_t)(t & 1) * B_ + bb) * H_ + seg * 32;
      u64 v[32];
#pragma unroll
      for (int i = 0; i < 32; ++i)
        v[i] = __hip_atomic_load(hp + i, __ATOMIC_RELAXED,
                                 __HIP_MEMORY_SCOPE_AGENT);
      for (;;) {
        bool ok = true;
#pragma unroll
        for (int i = 0; i < 32; ++i) ok &= ((unsigned)(v[i] >> 32) == tagt);
        if (ok) break;
#pragma unroll
        for (int i = 0; i < 32; ++i)
          if ((unsigned)(v[i] >> 32) != tagt)
            v[i] = __hip_atomic_load(hp + i, __ATOMIC_RELAXED,
                                     __HIP_MEMORY_SCOPE_AGENT);
      }
      float a = 0.f;
#pragma unroll
      for (int i = 0; i < 32; ++i)
        a += Rreg[i] * __uint_as_float((unsigned)v[i]);
      a += __shfl_xor(a, 1);
      a += __shfl_xor(a, 2);
      a += __shfl_xor(a, 4);
      if (seg == 0) recbuf[t & 1][bsel][j_local][g] = a + br;
    }
    __syncthreads();

    if (isGate) {
      float rz = recbuf[t & 1][gb][gj][0];
      float rr = recbuf[t & 1][gb][gj][1];
      float rh = recbuf[t & 1][gb][gj][2];
      float z  = 1.f / (1.f + expf(-(xz + rz)));
      float r  = 1.f / (1.f + expf(-(xr + rr)));
      float hh = tanhf(xh + r * rh);
      float hnew = z * hreg + (1.f - z) * hh;
      float hval = (tok != 0) ? hnew : hreg;
      hreg = hval;
      u64 pack = ((u64)(unsigned)(t + 1) << 32) | (u64)__float_as_uint(hval);
      __hip_atomic_store(hbuf + ((size_t)((t + 1) & 1) * B_ + gbb) * H_ + gjg,
                         pack, __ATOMIC_RELAXED, __HIP_MEMORY_SCOPE_AGENT);
      if (RETURN_SEQ) y[((size_t)gbb * T_ + t) * H_ + gjg] = hval;
    }
    // no trailing barrier: recbuf slot t&1 can only be overwritten at t+2,
    // which is transitively ordered after this step's gate reads via tags.
  }
}

// ---------------------------------------------------------------------------
// Final FC: out[b][c] = h[b] . fcW[:,c] + fcb[c]   (64x10, trivial)
// Final h (after step 511) sits in hbuf buffer 0 with tag 512.
// ---------------------------------------------------------------------------
__global__ void fc_kernel(const u64* __restrict__ hpack,  // hbuf[0]: [B][256]
                          const float* __restrict__ fcW,  // [256][10]
                          const float* __restrict__ fcb,
                          float* __restrict__ out) {
  int b = blockIdx.x;
  int c = threadIdx.x;
  if (c < 10) {
    float s = fcb[c];
    for (int k = 0; k < H_; ++k)
      s += __uint_as_float((unsigned)hpack[b * H_ + k]) * fcW[k * 10 + c];
    out[b * 10 + c] = s;
  }
}

// ---------------------------------------------------------------------------
extern "C" void kernel_launch(void* const* d_in, const int* in_sizes, int n_in,
                              void* d_out, int out_size, void* d_ws,
                              size_t ws_size, hipStream_t stream) {
  const int*   tokens = (const int*)d_in[0];
  const float* emb    = (const float*)d_in[1];
  const float* W      = (const float*)d_in[2];   // [5][256][768]
  const float* Rw     = (const float*)d_in[3];   // [5][256][768]
  const float* bi     = (const float*)d_in[4];   // [5][768]
  const float* br     = (const float*)d_in[5];   // [5][768]
  const float* fcW    = (const float*)d_in[6];   // [256][10]
  const float* fcb    = (const float*)d_in[7];   // [10]
  float*       out    = (float*)d_out;

  char* ws = (char*)d_ws;
  const size_t SEQ_BYTES = (size_t)B_ * T_ * D_ * 4;       // 33.5 MB
  float* x_buf  = (float*)(ws);
  float* y_buf  = (float*)(ws + SEQ_BYTES);
  float* xproj  = (float*)(ws + 2 * SEQ_BYTES);            // 100.7 MB
  u64*   hbuf   = (u64*)(ws + 2 * SEQ_BYTES + (size_t)B_ * T_ * G3_ * 4);

  embed_kernel<<<(B_ * T_) / 4, 256, 0, stream>>>(tokens, emb, x_buf);

  const float* in_seq = x_buf;
  float*       out_seq = y_buf;
  for (int l = 0; l < L_; ++l) {
    gemm_xproj<<<dim3(G3_ / 64, (B_ * T_) / 64), 256, 0, stream>>>(
        in_seq, W + (size_t)l * D_ * G3_, bi + (size_t)l * G3_, xproj);
    hipMemsetAsync(hbuf, 0, (size_t)2 * B_ * H_ * sizeof(u64), stream);
    if (l < L_ - 1) {
      scan_kernel<true><<<256, 768, 0, stream>>>(
          xproj, Rw + (size_t)l * D_ * G3_, br + (size_t)l * G3_, tokens,
          out_seq, hbuf);
    } else {
      scan_kernel<false><<<256, 768, 0, stream>>>(
          xproj, Rw + (size_t)l * D_ * G3_, br + (size_t)l * G3_, tokens,
          nullptr, hbuf);
    }
    const float* tmp = in_seq;
    in_seq = out_seq;
    out_seq = (float*)tmp;
  }
  fc_kernel<<<B_, 64, 0, stream>>>(hbuf, fcW, fcb, out);
}

// Round 5
// 16353.099 us; speedup vs baseline: 4.9786x; 4.3562x over previous
//
#include <hip/hip_runtime.h>

#define B_ 64
#define T_ 512
#define D_ 256
#define H_ 256
#define G3_ 768   // 3*H
#define L_ 5
#define RTS_L (G3_ * H_)   // 196608 elements per layer

// ---------------------------------------------------------------------------
// Embedding gather: x[row][d] = emb[tokens[row]][d], row in [0, B*T)
// ---------------------------------------------------------------------------
__global__ void embed_kernel(const int* __restrict__ tokens,
                             const float* __restrict__ emb,
                             float* __restrict__ x) {
  int row  = blockIdx.x * 4 + (threadIdx.x >> 6);
  int lane = threadIdx.x & 63;
  int tok  = tokens[row];
  const float4* src = (const float4*)(emb + (size_t)tok * D_);
  float4*       dst = (float4*)(x + (size_t)row * D_);
  dst[lane] = src[lane];
}

// ---------------------------------------------------------------------------
// Repack R into scan-friendly layout:
//   RTS[l][nblk][kq][lane][c] = R[l][kq*4+c][nblk*64+lane]
// so that in the scan, thread n at k-quad kq loads a float4 at
// ((n>>6)*64 + kq)*256 + (n&63)*4  -> 64 lanes read 1KB contiguous.
// Tiny (3.9 MB), runs once.
// ---------------------------------------------------------------------------
__global__ void make_rts(const float* __restrict__ R, float* __restrict__ RTS) {
  size_t i = (size_t)blockIdx.x * 256 + threadIdx.x;   // over 5*196608
  int l = (int)(i / RTS_L);
  int rem = (int)(i % RTS_L);
  int nblk = rem >> 14;
  int kq   = (rem >> 8) & 63;
  int lane = (rem >> 2) & 63;
  int c    = rem & 3;
  int n = nblk * 64 + lane;
  int k = kq * 4 + c;
  RTS[i] = R[(size_t)l * RTS_L + (size_t)k * G3_ + n];
}

// ---------------------------------------------------------------------------
// xproj GEMM: C[M=32768][768] = X[M][256] @ W[256][768] + bi
// ---------------------------------------------------------------------------
__global__ __launch_bounds__(256) void gemm_xproj(
    const float* __restrict__ X,
    const float* __restrict__ W,
    const float* __restrict__ bi,
    float* __restrict__ C) {
  __shared__ float As[16][68];
  __shared__ float Bs[16][64];
  const int tid = threadIdx.x;
  const int tx = tid & 15, ty = tid >> 4;
  const int m0 = blockIdx.y * 64;
  const int n0 = blockIdx.x * 64;
  const int lr = tid >> 2, lseg = tid & 3;
  const int wk = tid >> 4, wseg = tid & 15;

  float acc[4][4] = {};
  for (int k0 = 0; k0 < 256; k0 += 16) {
    float4 xv = *(const float4*)(X + (size_t)(m0 + lr) * D_ + k0 + lseg * 4);
    As[lseg * 4 + 0][lr] = xv.x;
    As[lseg * 4 + 1][lr] = xv.y;
    As[lseg * 4 + 2][lr] = xv.z;
    As[lseg * 4 + 3][lr] = xv.w;
    *(float4*)&Bs[wk][wseg * 4] =
        *(const float4*)(W + (size_t)(k0 + wk) * G3_ + n0 + wseg * 4);
    __syncthreads();
#pragma unroll
    for (int k = 0; k < 16; ++k) {
      float a[4], b[4];
      *(float4*)a = *(const float4*)&As[k][ty * 4];
      *(float4*)b = *(const float4*)&Bs[k][tx * 4];
#pragma unroll
      for (int q = 0; q < 4; ++q)
#pragma unroll
        for (int i = 0; i < 4; ++i) acc[q][i] += a[q] * b[i];
    }
    __syncthreads();
  }
  float4 bv = *(const float4*)(bi + n0 + tx * 4);
#pragma unroll
  for (int q = 0; q < 4; ++q) {
    float4 o;
    o.x = acc[q][0] + bv.x;
    o.y = acc[q][1] + bv.y;
    o.z = acc[q][2] + bv.z;
    o.w = acc[q][3] + bv.w;
    *(float4*)(C + (size_t)(m0 + ty * 4 + q) * G3_ + n0 + tx * 4) = o;
  }
}

// ---------------------------------------------------------------------------
// GRU scan, one batch per WG — ZERO cross-WG synchronization.
// Block = 768 threads (12 waves). Thread tid owns output column n = tid.
// Per step: dot(h, R[:,n]) with h broadcast from LDS, R streamed from L2
// (RTS layout, fully coalesced); rec -> LDS; gate threads (tid<256) update h.
// Two __syncthreads per step.
// ---------------------------------------------------------------------------
template <bool RETURN_SEQ>
__global__ __launch_bounds__(768, 3) void scan2_kernel(
    const float* __restrict__ xproj,   // [B][T][768]
    const float* __restrict__ RTS_l,   // repacked R, 196608 floats
    const float* __restrict__ brl,     // [768]
    const int* __restrict__ tokens,    // [B][T]
    float* __restrict__ y,             // [B][T][256] if RETURN_SEQ
    float* __restrict__ hfinal) {      // [B][256] if !RETURN_SEQ
  const int b   = blockIdx.x;
  const int tid = threadIdx.x;

  __shared__ float h_s[H_];      // current hidden state
  __shared__ float rec_s[G3_];   // recurrent projection z|r|h

  const float br = brl[tid];
  const float4* rts4 = (const float4*)RTS_l;
  const int rbase = (tid >> 6) * 4096 + (tid & 63);   // float4 units
  const float4* h4 = (const float4*)h_s;

  if (tid < H_) h_s[tid] = 0.f;
  __syncthreads();

  const float* xp_base = xproj + (size_t)b * T_ * G3_;
  const int*   tok_base = tokens + b * T_;

  for (int t = 0; t < T_; ++t) {
    // gate-input prefetch (waves 0-3), in flight during the dot
    float xz = 0.f, xr = 0.f, xh = 0.f;
    int tok = 0;
    if (tid < H_) {
      const float* xp = xp_base + (size_t)t * G3_ + tid;
      xz = xp[0];
      xr = xp[256];
      xh = xp[512];
      tok = tok_base[t];
    }

    // dot(h, R[:,n]) — R from L2 (coalesced 1KB/wave-load), h LDS broadcast
    float a = 0.f;
#pragma unroll 8
    for (int kq = 0; kq < 64; ++kq) {
      float4 rv = rts4[rbase + kq * 64];
      float4 hv = h4[kq];
      a = fmaf(rv.x, hv.x, a);
      a = fmaf(rv.y, hv.y, a);
      a = fmaf(rv.z, hv.z, a);
      a = fmaf(rv.w, hv.w, a);
    }
    rec_s[tid] = a + br;
    __syncthreads();

    if (tid < H_) {
      float rz = rec_s[tid];
      float rr = rec_s[H_ + tid];
      float rh = rec_s[2 * H_ + tid];
      float z  = 1.f / (1.f + expf(-(xz + rz)));
      float r  = 1.f / (1.f + expf(-(xr + rr)));
      float hh = tanhf(xh + r * rh);
      float hold = h_s[tid];
      float hnew = z * hold + (1.f - z) * hh;
      float hval = (tok != 0) ? hnew : hold;
      h_s[tid] = hval;
      if (RETURN_SEQ) {
        y[((size_t)b * T_ + t) * H_ + tid] = hval;
      }
    }
    __syncthreads();   // h_s update visible before next step's dot
  }

  if (!RETURN_SEQ && tid < H_) hfinal[(size_t)b * H_ + tid] = h_s[tid];
}

// ---------------------------------------------------------------------------
// Final FC: out[b][c] = h[b] . fcW[:,c] + fcb[c]   (64x10, trivial)
// ---------------------------------------------------------------------------
__global__ void fc_kernel(const float* __restrict__ h,    // [B][256]
                          const float* __restrict__ fcW,  // [256][10]
                          const float* __restrict__ fcb,
                          float* __restrict__ out) {
  int b = blockIdx.x;
  int c = threadIdx.x;
  if (c < 10) {
    float s = fcb[c];
    for (int k = 0; k < H_; ++k) s += h[b * H_ + k] * fcW[k * 10 + c];
    out[b * 10 + c] = s;
  }
}

// ---------------------------------------------------------------------------
extern "C" void kernel_launch(void* const* d_in, const int* in_sizes, int n_in,
                              void* d_out, int out_size, void* d_ws,
                              size_t ws_size, hipStream_t stream) {
  const int*   tokens = (const int*)d_in[0];
  const float* emb    = (const float*)d_in[1];
  const float* W      = (const float*)d_in[2];   // [5][256][768]
  const float* Rw     = (const float*)d_in[3];   // [5][256][768]
  const float* bi     = (const float*)d_in[4];   // [5][768]
  const float* br     = (const float*)d_in[5];   // [5][768]
  const float* fcW    = (const float*)d_in[6];   // [256][10]
  const float* fcb    = (const float*)d_in[7];   // [10]
  float*       out    = (float*)d_out;

  char* ws = (char*)d_ws;
  const size_t SEQ_BYTES = (size_t)B_ * T_ * D_ * 4;          // 33.55 MB
  const size_t XPJ_BYTES = (size_t)B_ * T_ * G3_ * 4;         // 100.7 MB
  float* x_buf  = (float*)(ws);
  float* y_buf  = (float*)(ws + SEQ_BYTES);
  float* xproj  = (float*)(ws + 2 * SEQ_BYTES);
  float* RTS    = (float*)(ws + 2 * SEQ_BYTES + XPJ_BYTES);
  float* hfinal = (float*)(ws + 2 * SEQ_BYTES + XPJ_BYTES +
                           (size_t)L_ * RTS_L * 4);

  embed_kernel<<<(B_ * T_) / 4, 256, 0, stream>>>(tokens, emb, x_buf);
  make_rts<<<(L_ * RTS_L) / 256, 256, 0, stream>>>(Rw, RTS);

  const float* in_seq = x_buf;
  float*       out_seq = y_buf;
  for (int l = 0; l < L_; ++l) {
    gemm_xproj<<<dim3(G3_ / 64, (B_ * T_) / 64), 256, 0, stream>>>(
        in_seq, W + (size_t)l * D_ * G3_, bi + (size_t)l * G3_, xproj);
    if (l < L_ - 1) {
      scan2_kernel<true><<<B_, 768, 0, stream>>>(
          xproj, RTS + (size_t)l * RTS_L, br + (size_t)l * G3_, tokens,
          out_seq, nullptr);
    } else {
      scan2_kernel<false><<<B_, 768, 0, stream>>>(
          xproj, RTS + (size_t)l * RTS_L, br + (size_t)l * G3_, tokens,
          nullptr, hfinal);
    }
    const float* tmp = in_seq;
    in_seq = out_seq;
    out_seq = (float*)tmp;
  }
  fc_kernel<<<B_, 64, 0, stream>>>(hfinal, fcW, fcb, out);
}

// Round 6
// 13712.793 us; speedup vs baseline: 5.9372x; 1.1925x over previous
//
#include <hip/hip_runtime.h>

#define B_ 64
#define T_ 512
#define D_ 256
#define H_ 256
#define G3_ 768   // 3*H
#define L_ 5
#define RTS_L (G3_ * H_)   // 196608 elements per layer
#define RQ_ 26             // k-quads of R held in VGPRs (104 VGPRs/thread)

// ---------------------------------------------------------------------------
// Embedding gather: x[row][d] = emb[tokens[row]][d], row in [0, B*T)
// ---------------------------------------------------------------------------
__global__ void embed_kernel(const int* __restrict__ tokens,
                             const float* __restrict__ emb,
                             float* __restrict__ x) {
  int row  = blockIdx.x * 4 + (threadIdx.x >> 6);
  int lane = threadIdx.x & 63;
  int tok  = tokens[row];
  const float4* src = (const float4*)(emb + (size_t)tok * D_);
  float4*       dst = (float4*)(x + (size_t)row * D_);
  dst[lane] = src[lane];
}

// ---------------------------------------------------------------------------
// Repack R into scan-friendly layout:
//   RTS[l][nblk][kq][lane][c] = R[l][kq*4+c][nblk*64+lane]
// Thread n at k-quad kq loads float4 at ((n>>6)*64 + kq)*256 + (n&63)*4
// -> 64 lanes read 1KB contiguous. Tiny (3.9 MB), runs once.
// ---------------------------------------------------------------------------
__global__ void make_rts(const float* __restrict__ R, float* __restrict__ RTS) {
  size_t i = (size_t)blockIdx.x * 256 + threadIdx.x;   // over 5*196608
  int l = (int)(i / RTS_L);
  int rem = (int)(i % RTS_L);
  int nblk = rem >> 14;
  int kq   = (rem >> 8) & 63;
  int lane = (rem >> 2) & 63;
  int c    = rem & 3;
  int n = nblk * 64 + lane;
  int k = kq * 4 + c;
  RTS[i] = R[(size_t)l * RTS_L + (size_t)k * G3_ + n];
}

// ---------------------------------------------------------------------------
// xproj GEMM: C[M=32768][768] = X[M][256] @ W[256][768] + bi
// ---------------------------------------------------------------------------
__global__ __launch_bounds__(256) void gemm_xproj(
    const float* __restrict__ X,
    const float* __restrict__ W,
    const float* __restrict__ bi,
    float* __restrict__ C) {
  __shared__ float As[16][68];
  __shared__ float Bs[16][64];
  const int tid = threadIdx.x;
  const int tx = tid & 15, ty = tid >> 4;
  const int m0 = blockIdx.y * 64;
  const int n0 = blockIdx.x * 64;
  const int lr = tid >> 2, lseg = tid & 3;
  const int wk = tid >> 4, wseg = tid & 15;

  float acc[4][4] = {};
  for (int k0 = 0; k0 < 256; k0 += 16) {
    float4 xv = *(const float4*)(X + (size_t)(m0 + lr) * D_ + k0 + lseg * 4);
    As[lseg * 4 + 0][lr] = xv.x;
    As[lseg * 4 + 1][lr] = xv.y;
    As[lseg * 4 + 2][lr] = xv.z;
    As[lseg * 4 + 3][lr] = xv.w;
    *(float4*)&Bs[wk][wseg * 4] =
        *(const float4*)(W + (size_t)(k0 + wk) * G3_ + n0 + wseg * 4);
    __syncthreads();
#pragma unroll
    for (int k = 0; k < 16; ++k) {
      float a[4], b[4];
      *(float4*)a = *(const float4*)&As[k][ty * 4];
      *(float4*)b = *(const float4*)&Bs[k][tx * 4];
#pragma unroll
      for (int q = 0; q < 4; ++q)
#pragma unroll
        for (int i = 0; i < 4; ++i) acc[q][i] += a[q] * b[i];
    }
    __syncthreads();
  }
  float4 bv = *(const float4*)(bi + n0 + tx * 4);
#pragma unroll
  for (int q = 0; q < 4; ++q) {
    float4 o;
    o.x = acc[q][0] + bv.x;
    o.y = acc[q][1] + bv.y;
    o.z = acc[q][2] + bv.z;
    o.w = acc[q][3] + bv.w;
    *(float4*)(C + (size_t)(m0 + ty * 4 + q) * G3_ + n0 + tx * 4) = o;
  }
}

// ---------------------------------------------------------------------------
// GRU scan, one batch per WG — zero cross-WG sync.
// Block = 768 threads (12 waves, 3/SIMD -> VGPR cap ~168). Thread tid owns
// output column n = tid. R column: first RQ_ k-quads resident in VGPRs
// (loaded once, 4*RQ_ VGPRs), remaining 64-RQ_ quads streamed from L2 per
// step. Per-CU L2 stream drops 768KB -> (64-RQ_)*12KB per step.
// ---------------------------------------------------------------------------
template <bool RETURN_SEQ>
__global__ __launch_bounds__(768, 3) void scan2_kernel(
    const float* __restrict__ xproj,   // [B][T][768]
    const float* __restrict__ RTS_l,   // repacked R, 196608 floats
    const float* __restrict__ brl,     // [768]
    const int* __restrict__ tokens,    // [B][T]
    float* __restrict__ y,             // [B][T][256] if RETURN_SEQ
    float* __restrict__ hfinal) {      // [B][256] if !RETURN_SEQ
  const int b   = blockIdx.x;
  const int tid = threadIdx.x;

  __shared__ float h_s[H_];      // current hidden state
  __shared__ float rec_s[G3_];   // recurrent projection z|r|h

  const float br = brl[tid];
  const float4* rts4 = (const float4*)RTS_l;
  const int rbase = (tid >> 6) * 4096 + (tid & 63);   // float4 units
  const float4* h4 = (const float4*)h_s;

  // Resident part of R column: RQ_ quads, static indices -> VGPRs.
  float4 Rreg[RQ_];
#pragma unroll
  for (int kq = 0; kq < RQ_; ++kq) Rreg[kq] = rts4[rbase + kq * 64];

  if (tid < H_) h_s[tid] = 0.f;
  __syncthreads();

  const float* xp_base = xproj + (size_t)b * T_ * G3_;
  const int*   tok_base = tokens + b * T_;

  for (int t = 0; t < T_; ++t) {
    // gate-input prefetch (waves 0-3), in flight during the dot
    float xz = 0.f, xr = 0.f, xh = 0.f;
    int tok = 0;
    if (tid < H_) {
      const float* xp = xp_base + (size_t)t * G3_ + tid;
      xz = xp[0];
      xr = xp[256];
      xh = xp[512];
      tok = tok_base[t];
    }

    // dot(h, R[:,n]) — register part + streamed part (L2, coalesced)
    float a = 0.f;
#pragma unroll
    for (int kq = 0; kq < RQ_; ++kq) {
      float4 rv = Rreg[kq];
      float4 hv = h4[kq];
      a = fmaf(rv.x, hv.x, a);
      a = fmaf(rv.y, hv.y, a);
      a = fmaf(rv.z, hv.z, a);
      a = fmaf(rv.w, hv.w, a);
    }
#pragma unroll 8
    for (int kq = RQ_; kq < 64; ++kq) {
      float4 rv = rts4[rbase + kq * 64];
      float4 hv = h4[kq];
      a = fmaf(rv.x, hv.x, a);
      a = fmaf(rv.y, hv.y, a);
      a = fmaf(rv.z, hv.z, a);
      a = fmaf(rv.w, hv.w, a);
    }
    rec_s[tid] = a + br;
    __syncthreads();

    if (tid < H_) {
      float rz = rec_s[tid];
      float rr = rec_s[H_ + tid];
      float rh = rec_s[2 * H_ + tid];
      float z  = 1.f / (1.f + expf(-(xz + rz)));
      float r  = 1.f / (1.f + expf(-(xr + rr)));
      float hh = tanhf(xh + r * rh);
      float hold = h_s[tid];
      float hnew = z * hold + (1.f - z) * hh;
      float hval = (tok != 0) ? hnew : hold;
      h_s[tid] = hval;
      if (RETURN_SEQ) {
        y[((size_t)b * T_ + t) * H_ + tid] = hval;
      }
    }
    __syncthreads();   // h_s update visible before next step's dot
  }

  if (!RETURN_SEQ && tid < H_) hfinal[(size_t)b * H_ + tid] = h_s[tid];
}

// ---------------------------------------------------------------------------
// Final FC: out[b][c] = h[b] . fcW[:,c] + fcb[c]   (64x10, trivial)
// ---------------------------------------------------------------------------
__global__ void fc_kernel(const float* __restrict__ h,    // [B][256]
                          const float* __restrict__ fcW,  // [256][10]
                          const float* __restrict__ fcb,
                          float* __restrict__ out) {
  int b = blockIdx.x;
  int c = threadIdx.x;
  if (c < 10) {
    float s = fcb[c];
    for (int k = 0; k < H_; ++k) s += h[b * H_ + k] * fcW[k * 10 + c];
    out[b * 10 + c] = s;
  }
}

// ---------------------------------------------------------------------------
extern "C" void kernel_launch(void* const* d_in, const int* in_sizes, int n_in,
                              void* d_out, int out_size, void* d_ws,
                              size_t ws_size, hipStream_t stream) {
  const int*   tokens = (const int*)d_in[0];
  const float* emb    = (const float*)d_in[1];
  const float* W      = (const float*)d_in[2];   // [5][256][768]
  const float* Rw     = (const float*)d_in[3];   // [5][256][768]
  const float* bi     = (const float*)d_in[4];   // [5][768]
  const float* br     = (const float*)d_in[5];   // [5][768]
  const float* fcW    = (const float*)d_in[6];   // [256][10]
  const float* fcb    = (const float*)d_in[7];   // [10]
  float*       out    = (float*)d_out;

  char* ws = (char*)d_ws;
  const size_t SEQ_BYTES = (size_t)B_ * T_ * D_ * 4;          // 33.55 MB
  const size_t XPJ_BYTES = (size_t)B_ * T_ * G3_ * 4;         // 100.7 MB
  float* x_buf  = (float*)(ws);
  float* y_buf  = (float*)(ws + SEQ_BYTES);
  float* xproj  = (float*)(ws + 2 * SEQ_BYTES);
  float* RTS    = (float*)(ws + 2 * SEQ_BYTES + XPJ_BYTES);
  float* hfinal = (float*)(ws + 2 * SEQ_BYTES + XPJ_BYTES +
                           (size_t)L_ * RTS_L * 4);

  embed_kernel<<<(B_ * T_) / 4, 256, 0, stream>>>(tokens, emb, x_buf);
  make_rts<<<(L_ * RTS_L) / 256, 256, 0, stream>>>(Rw, RTS);

  const float* in_seq = x_buf;
  float*       out_seq = y_buf;
  for (int l = 0; l < L_; ++l) {
    gemm_xproj<<<dim3(G3_ / 64, (B_ * T_) / 64), 256, 0, stream>>>(
        in_seq, W + (size_t)l * D_ * G3_, bi + (size_t)l * G3_, xproj);
    if (l < L_ - 1) {
      scan2_kernel<true><<<B_, 768, 0, stream>>>(
          xproj, RTS + (size_t)l * RTS_L, br + (size_t)l * G3_, tokens,
          out_seq, nullptr);
    } else {
      scan2_kernel<false><<<B_, 768, 0, stream>>>(
          xproj, RTS + (size_t)l * RTS_L, br + (size_t)l * G3_, tokens,
          nullptr, hfinal);
    }
    const float* tmp = in_seq;
    in_seq = out_seq;
    out_seq = (float*)tmp;
  }
  fc_kernel<<<B_, 64, 0, stream>>>(hfinal, fcW, fcb, out);
}

// Round 7
// 12874.738 us; speedup vs baseline: 6.3237x; 1.0651x over previous
//
#include <hip/hip_runtime.h>

#define B_ 64
#define T_ 512
#define D_ 256
#define H_ 256
#define G3_ 768   // 3*H
#define L_ 5
#define RTS_L (G3_ * H_)   // 196608 elements per layer
#define RQ_ 26             // k-quads of R pinned in VGPRs (104 VGPRs/thread)
#define LQ_ 4              // k-quads of R staged in LDS (48 KB)

// ---------------------------------------------------------------------------
// Embedding gather: x[row][d] = emb[tokens[row]][d], row in [0, B*T)
// ---------------------------------------------------------------------------
__global__ void embed_kernel(const int* __restrict__ tokens,
                             const float* __restrict__ emb,
                             float* __restrict__ x) {
  int row  = blockIdx.x * 4 + (threadIdx.x >> 6);
  int lane = threadIdx.x & 63;
  int tok  = tokens[row];
  const float4* src = (const float4*)(emb + (size_t)tok * D_);
  float4*       dst = (float4*)(x + (size_t)row * D_);
  dst[lane] = src[lane];
}

// ---------------------------------------------------------------------------
// Repack R into scan-friendly layout:
//   RTS[l][nblk][kq][lane][c] = R[l][kq*4+c][nblk*64+lane]
// Thread n at k-quad kq loads float4 at ((n>>6)*64 + kq)*256 + (n&63)*4
// -> 64 lanes read 1KB contiguous. Tiny (3.9 MB), runs once.
// ---------------------------------------------------------------------------
__global__ void make_rts(const float* __restrict__ R, float* __restrict__ RTS) {
  size_t i = (size_t)blockIdx.x * 256 + threadIdx.x;   // over 5*196608
  int l = (int)(i / RTS_L);
  int rem = (int)(i % RTS_L);
  int nblk = rem >> 14;
  int kq   = (rem >> 8) & 63;
  int lane = (rem >> 2) & 63;
  int c    = rem & 3;
  int n = nblk * 64 + lane;
  int k = kq * 4 + c;
  RTS[i] = R[(size_t)l * RTS_L + (size_t)k * G3_ + n];
}

// ---------------------------------------------------------------------------
// xproj GEMM: C[M=32768][768] = X[M][256] @ W[256][768] + bi
// ---------------------------------------------------------------------------
__global__ __launch_bounds__(256) void gemm_xproj(
    const float* __restrict__ X,
    const float* __restrict__ W,
    const float* __restrict__ bi,
    float* __restrict__ C) {
  __shared__ float As[16][68];
  __shared__ float Bs[16][64];
  const int tid = threadIdx.x;
  const int tx = tid & 15, ty = tid >> 4;
  const int m0 = blockIdx.y * 64;
  const int n0 = blockIdx.x * 64;
  const int lr = tid >> 2, lseg = tid & 3;
  const int wk = tid >> 4, wseg = tid & 15;

  float acc[4][4] = {};
  for (int k0 = 0; k0 < 256; k0 += 16) {
    float4 xv = *(const float4*)(X + (size_t)(m0 + lr) * D_ + k0 + lseg * 4);
    As[lseg * 4 + 0][lr] = xv.x;
    As[lseg * 4 + 1][lr] = xv.y;
    As[lseg * 4 + 2][lr] = xv.z;
    As[lseg * 4 + 3][lr] = xv.w;
    *(float4*)&Bs[wk][wseg * 4] =
        *(const float4*)(W + (size_t)(k0 + wk) * G3_ + n0 + wseg * 4);
    __syncthreads();
#pragma unroll
    for (int k = 0; k < 16; ++k) {
      float a[4], b[4];
      *(float4*)a = *(const float4*)&As[k][ty * 4];
      *(float4*)b = *(const float4*)&Bs[k][tx * 4];
#pragma unroll
      for (int q = 0; q < 4; ++q)
#pragma unroll
        for (int i = 0; i < 4; ++i) acc[q][i] += a[q] * b[i];
    }
    __syncthreads();
  }
  float4 bv = *(const float4*)(bi + n0 + tx * 4);
#pragma unroll
  for (int q = 0; q < 4; ++q) {
    float4 o;
    o.x = acc[q][0] + bv.x;
    o.y = acc[q][1] + bv.y;
    o.z = acc[q][2] + bv.z;
    o.w = acc[q][3] + bv.w;
    *(float4*)(C + (size_t)(m0 + ty * 4 + q) * G3_ + n0 + tx * 4) = o;
  }
}

// ---------------------------------------------------------------------------
// GRU scan, one batch per WG — zero cross-WG sync.
// Block = 768 threads (12 waves, 3/SIMD -> VGPR cap ~168). Thread tid owns
// output column n = tid. R column split three ways:
//   quads [0, RQ_): pinned in VGPRs via asm keep-alive (remat barrier —
//                   round-6 showed the allocator re-loads otherwise)
//   quads [RQ_, RQ_+LQ_): staged once in LDS (48 KB, 256 B/cy/CU)
//   quads [RQ_+LQ_, 64): streamed from L2 each step (~60 B/cy/CU straw)
// ---------------------------------------------------------------------------
template <bool RETURN_SEQ>
__global__ __launch_bounds__(768, 3) void scan2_kernel(
    const float* __restrict__ xproj,   // [B][T][768]
    const float* __restrict__ RTS_l,   // repacked R, 196608 floats
    const float* __restrict__ brl,     // [768]
    const int* __restrict__ tokens,    // [B][T]
    float* __restrict__ y,             // [B][T][256] if RETURN_SEQ
    float* __restrict__ hfinal) {      // [B][256] if !RETURN_SEQ
  const int b   = blockIdx.x;
  const int tid = threadIdx.x;

  __shared__ float h_s[H_];               // current hidden state (1 KB)
  __shared__ float rec_s[G3_];            // recurrent projection z|r|h (3 KB)
  __shared__ float4 R_lds4[LQ_ * G3_];    // staged R quads (48 KB)

  const float br = brl[tid];
  const float4* rts4 = (const float4*)RTS_l;
  const int rbase = (tid >> 6) * 4096 + (tid & 63);   // float4 units
  const float4* h4 = (const float4*)h_s;

  // Pinned part of R column: RQ_ quads -> VGPRs, made opaque so the
  // allocator cannot rematerialize the loads inside the loop.
  float4 Rreg[RQ_];
#pragma unroll
  for (int kq = 0; kq < RQ_; ++kq) Rreg[kq] = rts4[rbase + kq * 64];
#pragma unroll
  for (int kq = 0; kq < RQ_; ++kq)
    asm volatile("" : "+v"(Rreg[kq].x), "+v"(Rreg[kq].y),
                      "+v"(Rreg[kq].z), "+v"(Rreg[kq].w));

  // LDS-staged part: LQ_ quads for all 768 columns.
#pragma unroll
  for (int q = 0; q < LQ_; ++q)
    R_lds4[q * G3_ + tid] = rts4[rbase + (RQ_ + q) * 64];

  if (tid < H_) h_s[tid] = 0.f;
  __syncthreads();

  const float* xp_base = xproj + (size_t)b * T_ * G3_;
  const int*   tok_base = tokens + b * T_;

  for (int t = 0; t < T_; ++t) {
    // gate-input prefetch (waves 0-3), in flight during the dot
    float xz = 0.f, xr = 0.f, xh = 0.f;
    int tok = 0;
    if (tid < H_) {
      const float* xp = xp_base + (size_t)t * G3_ + tid;
      xz = xp[0];
      xr = xp[256];
      xh = xp[512];
      tok = tok_base[t];
    }

    // dot(h, R[:,n]) — VGPR part + LDS part + streamed part
    float a = 0.f;
#pragma unroll
    for (int kq = 0; kq < RQ_; ++kq) {
      float4 rv = Rreg[kq];
      float4 hv = h4[kq];
      a = fmaf(rv.x, hv.x, a);
      a = fmaf(rv.y, hv.y, a);
      a = fmaf(rv.z, hv.z, a);
      a = fmaf(rv.w, hv.w, a);
    }
#pragma unroll
    for (int q = 0; q < LQ_; ++q) {
      float4 rv = R_lds4[q * G3_ + tid];
      float4 hv = h4[RQ_ + q];
      a = fmaf(rv.x, hv.x, a);
      a = fmaf(rv.y, hv.y, a);
      a = fmaf(rv.z, hv.z, a);
      a = fmaf(rv.w, hv.w, a);
    }
#pragma unroll 8
    for (int kq = RQ_ + LQ_; kq < 64; ++kq) {
      float4 rv = rts4[rbase + kq * 64];
      float4 hv = h4[kq];
      a = fmaf(rv.x, hv.x, a);
      a = fmaf(rv.y, hv.y, a);
      a = fmaf(rv.z, hv.z, a);
      a = fmaf(rv.w, hv.w, a);
    }
    rec_s[tid] = a + br;
    __syncthreads();

    if (tid < H_) {
      float rz = rec_s[tid];
      float rr = rec_s[H_ + tid];
      float rh = rec_s[2 * H_ + tid];
      float z  = 1.f / (1.f + expf(-(xz + rz)));
      float r  = 1.f / (1.f + expf(-(xr + rr)));
      float hh = tanhf(xh + r * rh);
      float hold = h_s[tid];
      float hnew = z * hold + (1.f - z) * hh;
      float hval = (tok != 0) ? hnew : hold;
      h_s[tid] = hval;
      if (RETURN_SEQ) {
        y[((size_t)b * T_ + t) * H_ + tid] = hval;
      }
    }
    __syncthreads();   // h_s update visible before next step's dot
  }

  if (!RETURN_SEQ && tid < H_) hfinal[(size_t)b * H_ + tid] = h_s[tid];
}

// ---------------------------------------------------------------------------
// Final FC: out[b][c] = h[b] . fcW[:,c] + fcb[c]   (64x10, trivial)
// ---------------------------------------------------------------------------
__global__ void fc_kernel(const float* __restrict__ h,    // [B][256]
                          const float* __restrict__ fcW,  // [256][10]
                          const float* __restrict__ fcb,
                          float* __restrict__ out) {
  int b = blockIdx.x;
  int c = threadIdx.x;
  if (c < 10) {
    float s = fcb[c];
    for (int k = 0; k < H_; ++k) s += h[b * H_ + k] * fcW[k * 10 + c];
    out[b * 10 + c] = s;
  }
}

// ---------------------------------------------------------------------------
extern "C" void kernel_launch(void* const* d_in, const int* in_sizes, int n_in,
                              void* d_out, int out_size, void* d_ws,
                              size_t ws_size, hipStream_t stream) {
  const int*   tokens = (const int*)d_in[0];
  const float* emb    = (const float*)d_in[1];
  const float* W      = (const float*)d_in[2];   // [5][256][768]
  const float* Rw     = (const float*)d_in[3];   // [5][256][768]
  const float* bi     = (const float*)d_in[4];   // [5][768]
  const float* br     = (const float*)d_in[5];   // [5][768]
  const float* fcW    = (const float*)d_in[6];   // [256][10]
  const float* fcb    = (const float*)d_in[7];   // [10]
  float*       out    = (float*)d_out;

  char* ws = (char*)d_ws;
  const size_t SEQ_BYTES = (size_t)B_ * T_ * D_ * 4;          // 33.55 MB
  const size_t XPJ_BYTES = (size_t)B_ * T_ * G3_ * 4;         // 100.7 MB
  float* x_buf  = (float*)(ws);
  float* y_buf  = (float*)(ws + SEQ_BYTES);
  float* xproj  = (float*)(ws + 2 * SEQ_BYTES);
  float* RTS    = (float*)(ws + 2 * SEQ_BYTES + XPJ_BYTES);
  float* hfinal = (float*)(ws + 2 * SEQ_BYTES + XPJ_BYTES +
                           (size_t)L_ * RTS_L * 4);

  embed_kernel<<<(B_ * T_) / 4, 256, 0, stream>>>(tokens, emb, x_buf);
  make_rts<<<(L_ * RTS_L) / 256, 256, 0, stream>>>(Rw, RTS);

  const float* in_seq = x_buf;
  float*       out_seq = y_buf;
  for (int l = 0; l < L_; ++l) {
    gemm_xproj<<<dim3(G3_ / 64, (B_ * T_) / 64), 256, 0, stream>>>(
        in_seq, W + (size_t)l * D_ * G3_, bi + (size_t)l * G3_, xproj);
    if (l < L_ - 1) {
      scan2_kernel<true><<<B_, 768, 0, stream>>>(
          xproj, RTS + (size_t)l * RTS_L, br + (size_t)l * G3_, tokens,
          out_seq, nullptr);
    } else {
      scan2_kernel<false><<<B_, 768, 0, stream>>>(
          xproj, RTS + (size_t)l * RTS_L, br + (size_t)l * G3_, tokens,
          nullptr, hfinal);
    }
    const float* tmp = in_seq;
    in_seq = out_seq;
    out_seq = (float*)tmp;
  }
  fc_kernel<<<B_, 64, 0, stream>>>(hfinal, fcW, fcb, out);
}

// Round 8
// 12821.892 us; speedup vs baseline: 6.3497x; 1.0041x over previous
//
#include <hip/hip_runtime.h>

#define B_ 64
#define T_ 512
#define D_ 256
#define H_ 256
#define G3_ 768   // 3*H
#define L_ 5
#define RTS_L (G3_ * H_)   // 196608 elements per layer
#define RQ_ 24             // k-quads of R pinned in VGPRs (96 VGPRs/thread)
#define LQ_ 12             // k-quads of R staged in LDS (144 KB)

// ---------------------------------------------------------------------------
// Embedding gather: x[row][d] = emb[tokens[row]][d], row in [0, B*T)
// ---------------------------------------------------------------------------
__global__ void embed_kernel(const int* __restrict__ tokens,
                             const float* __restrict__ emb,
                             float* __restrict__ x) {
  int row  = blockIdx.x * 4 + (threadIdx.x >> 6);
  int lane = threadIdx.x & 63;
  int tok  = tokens[row];
  const float4* src = (const float4*)(emb + (size_t)tok * D_);
  float4*       dst = (float4*)(x + (size_t)row * D_);
  dst[lane] = src[lane];
}

// ---------------------------------------------------------------------------
// Repack R into scan-friendly layout:
//   RTS[l][nblk][kq][lane][c] = R[l][kq*4+c][nblk*64+lane]
// Thread n at k-quad kq loads float4 at ((n>>6)*64 + kq)*256 + (n&63)*4
// -> 64 lanes read 1KB contiguous. Tiny (3.9 MB), runs once.
// ---------------------------------------------------------------------------
__global__ void make_rts(const float* __restrict__ R, float* __restrict__ RTS) {
  size_t i = (size_t)blockIdx.x * 256 + threadIdx.x;   // over 5*196608
  int l = (int)(i / RTS_L);
  int rem = (int)(i % RTS_L);
  int nblk = rem >> 14;
  int kq   = (rem >> 8) & 63;
  int lane = (rem >> 2) & 63;
  int c    = rem & 3;
  int n = nblk * 64 + lane;
  int k = kq * 4 + c;
  RTS[i] = R[(size_t)l * RTS_L + (size_t)k * G3_ + n];
}

// ---------------------------------------------------------------------------
// xproj GEMM: C[M=32768][768] = X[M][256] @ W[256][768] + bi
// ---------------------------------------------------------------------------
__global__ __launch_bounds__(256) void gemm_xproj(
    const float* __restrict__ X,
    const float* __restrict__ W,
    const float* __restrict__ bi,
    float* __restrict__ C) {
  __shared__ float As[16][68];
  __shared__ float Bs[16][64];
  const int tid = threadIdx.x;
  const int tx = tid & 15, ty = tid >> 4;
  const int m0 = blockIdx.y * 64;
  const int n0 = blockIdx.x * 64;
  const int lr = tid >> 2, lseg = tid & 3;
  const int wk = tid >> 4, wseg = tid & 15;

  float acc[4][4] = {};
  for (int k0 = 0; k0 < 256; k0 += 16) {
    float4 xv = *(const float4*)(X + (size_t)(m0 + lr) * D_ + k0 + lseg * 4);
    As[lseg * 4 + 0][lr] = xv.x;
    As[lseg * 4 + 1][lr] = xv.y;
    As[lseg * 4 + 2][lr] = xv.z;
    As[lseg * 4 + 3][lr] = xv.w;
    *(float4*)&Bs[wk][wseg * 4] =
        *(const float4*)(W + (size_t)(k0 + wk) * G3_ + n0 + wseg * 4);
    __syncthreads();
#pragma unroll
    for (int k = 0; k < 16; ++k) {
      float a[4], b[4];
      *(float4*)a = *(const float4*)&As[k][ty * 4];
      *(float4*)b = *(const float4*)&Bs[k][tx * 4];
#pragma unroll
      for (int q = 0; q < 4; ++q)
#pragma unroll
        for (int i = 0; i < 4; ++i) acc[q][i] += a[q] * b[i];
    }
    __syncthreads();
  }
  float4 bv = *(const float4*)(bi + n0 + tx * 4);
#pragma unroll
  for (int q = 0; q < 4; ++q) {
    float4 o;
    o.x = acc[q][0] + bv.x;
    o.y = acc[q][1] + bv.y;
    o.z = acc[q][2] + bv.z;
    o.w = acc[q][3] + bv.w;
    *(float4*)(C + (size_t)(m0 + ty * 4 + q) * G3_ + n0 + tx * 4) = o;
  }
}

// ---------------------------------------------------------------------------
// GRU scan, one batch per WG — zero cross-WG sync.
// Block = 768 threads (12 waves, 3/SIMD -> VGPR cap ~168). Thread tid owns
// output column n = tid. R column split three ways:
//   quads [0, RQ_): pinned in VGPRs (96 regs; budget 96+~45 < 168 so the
//                   allocator keeps them — round 7 spilled at 104+~70)
//   quads [RQ_, RQ_+LQ_): staged once in LDS (144 KB, ~85 B/cy, own pipe)
//   quads [RQ_+LQ_, 64): streamed from L2 each step (~60 B/cy/CU straw),
//                        unroll 4 to cap in-flight register pressure
// ---------------------------------------------------------------------------
template <bool RETURN_SEQ>
__global__ __launch_bounds__(768, 3) void scan2_kernel(
    const float* __restrict__ xproj,   // [B][T][768]
    const float* __restrict__ RTS_l,   // repacked R, 196608 floats
    const float* __restrict__ brl,     // [768]
    const int* __restrict__ tokens,    // [B][T]
    float* __restrict__ y,             // [B][T][256] if RETURN_SEQ
    float* __restrict__ hfinal) {      // [B][256] if !RETURN_SEQ
  const int b   = blockIdx.x;
  const int tid = threadIdx.x;

  __shared__ float h_s[H_];               // current hidden state (1 KB)
  __shared__ float rec_s[G3_];            // recurrent projection z|r|h (3 KB)
  __shared__ float4 R_lds4[LQ_ * G3_];    // staged R quads (144 KB)

  const float br = brl[tid];
  const float4* rts4 = (const float4*)RTS_l;
  const int rbase = (tid >> 6) * 4096 + (tid & 63);   // float4 units
  const float4* h4 = (const float4*)h_s;

  // Pinned part of R column: RQ_ quads -> VGPRs, opaque to remat.
  float4 Rreg[RQ_];
#pragma unroll
  for (int kq = 0; kq < RQ_; ++kq) Rreg[kq] = rts4[rbase + kq * 64];
#pragma unroll
  for (int kq = 0; kq < RQ_; ++kq)
    asm volatile("" : "+v"(Rreg[kq].x), "+v"(Rreg[kq].y),
                      "+v"(Rreg[kq].z), "+v"(Rreg[kq].w));

  // LDS-staged part: LQ_ quads for all 768 columns.
#pragma unroll
  for (int q = 0; q < LQ_; ++q)
    R_lds4[q * G3_ + tid] = rts4[rbase + (RQ_ + q) * 64];

  if (tid < H_) h_s[tid] = 0.f;
  __syncthreads();

  const float* xp_base = xproj + (size_t)b * T_ * G3_;
  const int*   tok_base = tokens + b * T_;

  for (int t = 0; t < T_; ++t) {
    // gate-input prefetch (waves 0-3), in flight during the dot
    float xz = 0.f, xr = 0.f, xh = 0.f;
    int tok = 0;
    if (tid < H_) {
      const float* xp = xp_base + (size_t)t * G3_ + tid;
      xz = xp[0];
      xr = xp[256];
      xh = xp[512];
      tok = tok_base[t];
    }

    // dot(h, R[:,n]) — VGPR part + LDS part + streamed part
    float a = 0.f;
#pragma unroll
    for (int kq = 0; kq < RQ_; ++kq) {
      float4 rv = Rreg[kq];
      float4 hv = h4[kq];
      a = fmaf(rv.x, hv.x, a);
      a = fmaf(rv.y, hv.y, a);
      a = fmaf(rv.z, hv.z, a);
      a = fmaf(rv.w, hv.w, a);
    }
#pragma unroll
    for (int q = 0; q < LQ_; ++q) {
      float4 rv = R_lds4[q * G3_ + tid];
      float4 hv = h4[RQ_ + q];
      a = fmaf(rv.x, hv.x, a);
      a = fmaf(rv.y, hv.y, a);
      a = fmaf(rv.z, hv.z, a);
      a = fmaf(rv.w, hv.w, a);
    }
#pragma unroll 4
    for (int kq = RQ_ + LQ_; kq < 64; ++kq) {
      float4 rv = rts4[rbase + kq * 64];
      float4 hv = h4[kq];
      a = fmaf(rv.x, hv.x, a);
      a = fmaf(rv.y, hv.y, a);
      a = fmaf(rv.z, hv.z, a);
      a = fmaf(rv.w, hv.w, a);
    }
    rec_s[tid] = a + br;
    __syncthreads();

    if (tid < H_) {
      float rz = rec_s[tid];
      float rr = rec_s[H_ + tid];
      float rh = rec_s[2 * H_ + tid];
      float z  = 1.f / (1.f + expf(-(xz + rz)));
      float r  = 1.f / (1.f + expf(-(xr + rr)));
      float hh = tanhf(xh + r * rh);
      float hold = h_s[tid];
      float hnew = z * hold + (1.f - z) * hh;
      float hval = (tok != 0) ? hnew : hold;
      h_s[tid] = hval;
      if (RETURN_SEQ) {
        y[((size_t)b * T_ + t) * H_ + tid] = hval;
      }
    }
    __syncthreads();   // h_s update visible before next step's dot
  }

  if (!RETURN_SEQ && tid < H_) hfinal[(size_t)b * H_ + tid] = h_s[tid];
}

// ---------------------------------------------------------------------------
// Final FC: out[b][c] = h[b] . fcW[:,c] + fcb[c]   (64x10, trivial)
// ---------------------------------------------------------------------------
__global__ void fc_kernel(const float* __restrict__ h,    // [B][256]
                          const float* __restrict__ fcW,  // [256][10]
                          const float* __restrict__ fcb,
                          float* __restrict__ out) {
  int b = blockIdx.x;
  int c = threadIdx.x;
  if (c < 10) {
    float s = fcb[c];
    for (int k = 0; k < H_; ++k) s += h[b * H_ + k] * fcW[k * 10 + c];
    out[b * 10 + c] = s;
  }
}

// ---------------------------------------------------------------------------
extern "C" void kernel_launch(void* const* d_in, const int* in_sizes, int n_in,
                              void* d_out, int out_size, void* d_ws,
                              size_t ws_size, hipStream_t stream) {
  const int*   tokens = (const int*)d_in[0];
  const float* emb    = (const float*)d_in[1];
  const float* W      = (const float*)d_in[2];   // [5][256][768]
  const float* Rw     = (const float*)d_in[3];   // [5][256][768]
  const float* bi     = (const float*)d_in[4];   // [5][768]
  const float* br     = (const float*)d_in[5];   // [5][768]
  const float* fcW    = (const float*)d_in[6];   // [256][10]
  const float* fcb    = (const float*)d_in[7];   // [10]
  float*       out    = (float*)d_out;

  char* ws = (char*)d_ws;
  const size_t SEQ_BYTES = (size_t)B_ * T_ * D_ * 4;          // 33.55 MB
  const size_t XPJ_BYTES = (size_t)B_ * T_ * G3_ * 4;         // 100.7 MB
  float* x_buf  = (float*)(ws);
  float* y_buf  = (float*)(ws + SEQ_BYTES);
  float* xproj  = (float*)(ws + 2 * SEQ_BYTES);
  float* RTS    = (float*)(ws + 2 * SEQ_BYTES + XPJ_BYTES);
  float* hfinal = (float*)(ws + 2 * SEQ_BYTES + XPJ_BYTES +
                           (size_t)L_ * RTS_L * 4);

  embed_kernel<<<(B_ * T_) / 4, 256, 0, stream>>>(tokens, emb, x_buf);
  make_rts<<<(L_ * RTS_L) / 256, 256, 0, stream>>>(Rw, RTS);

  const float* in_seq = x_buf;
  float*       out_seq = y_buf;
  for (int l = 0; l < L_; ++l) {
    gemm_xproj<<<dim3(G3_ / 64, (B_ * T_) / 64), 256, 0, stream>>>(
        in_seq, W + (size_t)l * D_ * G3_, bi + (size_t)l * G3_, xproj);
    if (l < L_ - 1) {
      scan2_kernel<true><<<B_, 768, 0, stream>>>(
          xproj, RTS + (size_t)l * RTS_L, br + (size_t)l * G3_, tokens,
          out_seq, nullptr);
    } else {
      scan2_kernel<false><<<B_, 768, 0, stream>>>(
          xproj, RTS + (size_t)l * RTS_L, br + (size_t)l * G3_, tokens,
          nullptr, hfinal);
    }
    const float* tmp = in_seq;
    in_seq = out_seq;
    out_seq = (float*)tmp;
  }
  fc_kernel<<<B_, 64, 0, stream>>>(hfinal, fcW, fcb, out);
}

// Round 10
// 10860.341 us; speedup vs baseline: 7.4966x; 1.1806x over previous
//
#include <hip/hip_runtime.h>

#define B_ 64
#define T_ 512
#define D_ 256
#define H_ 256
#define G3_ 768   // 3*H
#define L_ 5
#define RTS_L (G3_ * H_)   // 196608 elements per layer
#define RQ_ 22             // k-quads of R pinned in VGPRs (88 VGPRs/thread)
#define LQ_ 12             // k-quads of R staged in LDS (144 KB)

// ---------------------------------------------------------------------------
// Embedding gather: x[row][d] = emb[tokens[row]][d], row in [0, B*T)
// ---------------------------------------------------------------------------
__global__ void embed_kernel(const int* __restrict__ tokens,
                             const float* __restrict__ emb,
                             float* __restrict__ x) {
  int row  = blockIdx.x * 4 + (threadIdx.x >> 6);
  int lane = threadIdx.x & 63;
  int tok  = tokens[row];
  const float4* src = (const float4*)(emb + (size_t)tok * D_);
  float4*       dst = (float4*)(x + (size_t)row * D_);
  dst[lane] = src[lane];
}

// ---------------------------------------------------------------------------
// Repack R into scan-friendly layout:
//   RTS[l][nblk][kq][lane][c] = R[l][kq*4+c][nblk*64+lane]
// Thread n at k-quad kq loads float4 at ((n>>6)*64 + kq)*256 + (n&63)*4
// -> 64 lanes read 1KB contiguous. Tiny (3.9 MB), runs once.
// ---------------------------------------------------------------------------
__global__ void make_rts(const float* __restrict__ R, float* __restrict__ RTS) {
  size_t i = (size_t)blockIdx.x * 256 + threadIdx.x;   // over 5*196608
  int l = (int)(i / RTS_L);
  int rem = (int)(i % RTS_L);
  int nblk = rem >> 14;
  int kq   = (rem >> 8) & 63;
  int lane = (rem >> 2) & 63;
  int c    = rem & 3;
  int n = nblk * 64 + lane;
  int k = kq * 4 + c;
  RTS[i] = R[(size_t)l * RTS_L + (size_t)k * G3_ + n];
}

// ---------------------------------------------------------------------------
// xproj GEMM: C[M=32768][768] = X[M][256] @ W[256][768] + bi
// ---------------------------------------------------------------------------
__global__ __launch_bounds__(256) void gemm_xproj(
    const float* __restrict__ X,
    const float* __restrict__ W,
    const float* __restrict__ bi,
    float* __restrict__ C) {
  __shared__ float As[16][68];
  __shared__ float Bs[16][64];
  const int tid = threadIdx.x;
  const int tx = tid & 15, ty = tid >> 4;
  const int m0 = blockIdx.y * 64;
  const int n0 = blockIdx.x * 64;
  const int lr = tid >> 2, lseg = tid & 3;
  const int wk = tid >> 4, wseg = tid & 15;

  float acc[4][4] = {};
  for (int k0 = 0; k0 < 256; k0 += 16) {
    float4 xv = *(const float4*)(X + (size_t)(m0 + lr) * D_ + k0 + lseg * 4);
    As[lseg * 4 + 0][lr] = xv.x;
    As[lseg * 4 + 1][lr] = xv.y;
    As[lseg * 4 + 2][lr] = xv.z;
    As[lseg * 4 + 3][lr] = xv.w;
    *(float4*)&Bs[wk][wseg * 4] =
        *(const float4*)(W + (size_t)(k0 + wk) * G3_ + n0 + wseg * 4);
    __syncthreads();
#pragma unroll
    for (int k = 0; k < 16; ++k) {
      float a[4], b[4];
      *(float4*)a = *(const float4*)&As[k][ty * 4];
      *(float4*)b = *(const float4*)&Bs[k][tx * 4];
#pragma unroll
      for (int q = 0; q < 4; ++q)
#pragma unroll
        for (int i = 0; i < 4; ++i) acc[q][i] += a[q] * b[i];
    }
    __syncthreads();
  }
  float4 bv = *(const float4*)(bi + n0 + tx * 4);
#pragma unroll
  for (int q = 0; q < 4; ++q) {
    float4 o;
    o.x = acc[q][0] + bv.x;
    o.y = acc[q][1] + bv.y;
    o.z = acc[q][2] + bv.z;
    o.w = acc[q][3] + bv.w;
    *(float4*)(C + (size_t)(m0 + ty * 4 + q) * G3_ + n0 + tx * 4) = o;
  }
}

// ---------------------------------------------------------------------------
// GRU scan, one batch per WG — zero cross-WG sync.
// Block = 768 threads (12 waves). LDS 148KB forces 1 WG/CU = 3 waves/SIMD,
// so amdgpu_waves_per_eu(3,3) tells the allocator the truth: budget 168
// VGPRs. (launch_bounds(768,3) only sets a MINIMUM; rounds 7-8 showed the
// allocator targeting 6 waves/EU at 84 regs and spilling the pinned R to
// scratch — which is L2-backed, i.e. re-streamed every step.)
// R column split: quads [0,RQ_) in VGPRs; [RQ_,RQ_+LQ_) in LDS;
// [RQ_+LQ_,64) streamed from L2 (~60 B/cy/CU straw).
// ---------------------------------------------------------------------------
template <bool RETURN_SEQ>
__global__ __attribute__((amdgpu_flat_work_group_size(768, 768)))
__attribute__((amdgpu_waves_per_eu(3, 3))) void scan2_kernel(
    const float* __restrict__ xproj,   // [B][T][768]
    const float* __restrict__ RTS_l,   // repacked R, 196608 floats
    const float* __restrict__ brl,     // [768]
    const int* __restrict__ tokens,    // [B][T]
    float* __restrict__ y,             // [B][T][256] if RETURN_SEQ
    float* __restrict__ hfinal) {      // [B][256] if !RETURN_SEQ
  const int b   = blockIdx.x;
  const int tid = threadIdx.x;

  __shared__ float h_s[H_];               // current hidden state (1 KB)
  __shared__ float rec_s[G3_];            // recurrent projection z|r|h (3 KB)
  __shared__ float4 R_lds4[LQ_ * G3_];    // staged R quads (144 KB)

  const float br = brl[tid];
  const float4* rts4 = (const float4*)RTS_l;
  const int rbase = (tid >> 6) * 4096 + (tid & 63);   // float4 units
  const float4* h4 = (const float4*)h_s;

  // Pinned part of R column: RQ_ quads -> VGPRs, opaque to remat.
  float4 Rreg[RQ_];
#pragma unroll
  for (int kq = 0; kq < RQ_; ++kq) Rreg[kq] = rts4[rbase + kq * 64];
#pragma unroll
  for (int kq = 0; kq < RQ_; ++kq)
    asm volatile("" : "+v"(Rreg[kq].x), "+v"(Rreg[kq].y),
                      "+v"(Rreg[kq].z), "+v"(Rreg[kq].w));

  // LDS-staged part: LQ_ quads for all 768 columns.
#pragma unroll
  for (int q = 0; q < LQ_; ++q)
    R_lds4[q * G3_ + tid] = rts4[rbase + (RQ_ + q) * 64];

  if (tid < H_) h_s[tid] = 0.f;
  __syncthreads();

  const float* xp_base = xproj + (size_t)b * T_ * G3_;
  const int*   tok_base = tokens + b * T_;

  for (int t = 0; t < T_; ++t) {
    // gate-input prefetch (waves 0-3), in flight during the dot
    float xz = 0.f, xr = 0.f, xh = 0.f;
    int tok = 0;
    if (tid < H_) {
      const float* xp = xp_base + (size_t)t * G3_ + tid;
      xz = xp[0];
      xr = xp[256];
      xh = xp[512];
      tok = tok_base[t];
    }

    // dot(h, R[:,n]) — VGPR part + LDS part + streamed part
    float a = 0.f;
#pragma unroll
    for (int kq = 0; kq < RQ_; ++kq) {
      float4 rv = Rreg[kq];
      float4 hv = h4[kq];
      a = fmaf(rv.x, hv.x, a);
      a = fmaf(rv.y, hv.y, a);
      a = fmaf(rv.z, hv.z, a);
      a = fmaf(rv.w, hv.w, a);
    }
#pragma unroll
    for (int q = 0; q < LQ_; ++q) {
      float4 rv = R_lds4[q * G3_ + tid];
      float4 hv = h4[RQ_ + q];
      a = fmaf(rv.x, hv.x, a);
      a = fmaf(rv.y, hv.y, a);
      a = fmaf(rv.z, hv.z, a);
      a = fmaf(rv.w, hv.w, a);
    }
#pragma unroll 4
    for (int kq = RQ_ + LQ_; kq < 64; ++kq) {
      float4 rv = rts4[rbase + kq * 64];
      float4 hv = h4[kq];
      a = fmaf(rv.x, hv.x, a);
      a = fmaf(rv.y, hv.y, a);
      a = fmaf(rv.z, hv.z, a);
      a = fmaf(rv.w, hv.w, a);
    }
    rec_s[tid] = a + br;
    __syncthreads();

    if (tid < H_) {
      float rz = rec_s[tid];
      float rr = rec_s[H_ + tid];
      float rh = rec_s[2 * H_ + tid];
      float z  = 1.f / (1.f + expf(-(xz + rz)));
      float r  = 1.f / (1.f + expf(-(xr + rr)));
      float hh = tanhf(xh + r * rh);
      float hold = h_s[tid];
      float hnew = z * hold + (1.f - z) * hh;
      float hval = (tok != 0) ? hnew : hold;
      h_s[tid] = hval;
      if (RETURN_SEQ) {
        y[((size_t)b * T_ + t) * H_ + tid] = hval;
      }
    }
    __syncthreads();   // h_s update visible before next step's dot
  }

  if (!RETURN_SEQ && tid < H_) hfinal[(size_t)b * H_ + tid] = h_s[tid];
}

// ---------------------------------------------------------------------------
// Final FC: out[b][c] = h[b] . fcW[:,c] + fcb[c]   (64x10, trivial)
// ---------------------------------------------------------------------------
__global__ void fc_kernel(const float* __restrict__ h,    // [B][256]
                          const float* __restrict__ fcW,  // [256][10]
                          const float* __restrict__ fcb,
                          float* __restrict__ out) {
  int b = blockIdx.x;
  int c = threadIdx.x;
  if (c < 10) {
    float s = fcb[c];
    for (int k = 0; k < H_; ++k) s += h[b * H_ + k] * fcW[k * 10 + c];
    out[b * 10 + c] = s;
  }
}

// ---------------------------------------------------------------------------
extern "C" void kernel_launch(void* const* d_in, const int* in_sizes, int n_in,
                              void* d_out, int out_size, void* d_ws,
                              size_t ws_size, hipStream_t stream) {
  const int*   tokens = (const int*)d_in[0];
  const float* emb    = (const float*)d_in[1];
  const float* W      = (const float*)d_in[2];   // [5][256][768]
  const float* Rw     = (const float*)d_in[3];   // [5][256][768]
  const float* bi     = (const float*)d_in[4];   // [5][768]
  const float* br     = (const float*)d_in[5];   // [5][768]
  const float* fcW    = (const float*)d_in[6];   // [256][10]
  const float* fcb    = (const float*)d_in[7];   // [10]
  float*       out    = (float*)d_out;

  char* ws = (char*)d_ws;
  const size_t SEQ_BYTES = (size_t)B_ * T_ * D_ * 4;          // 33.55 MB
  const size_t XPJ_BYTES = (size_t)B_ * T_ * G3_ * 4;         // 100.7 MB
  float* x_buf  = (float*)(ws);
  float* y_buf  = (float*)(ws + SEQ_BYTES);
  float* xproj  = (float*)(ws + 2 * SEQ_BYTES);
  float* RTS    = (float*)(ws + 2 * SEQ_BYTES + XPJ_BYTES);
  float* hfinal = (float*)(ws + 2 * SEQ_BYTES + XPJ_BYTES +
                           (size_t)L_ * RTS_L * 4);

  embed_kernel<<<(B_ * T_) / 4, 256, 0, stream>>>(tokens, emb, x_buf);
  make_rts<<<(L_ * RTS_L) / 256, 256, 0, stream>>>(Rw, RTS);

  const float* in_seq = x_buf;
  float*       out_seq = y_buf;
  for (int l = 0; l < L_; ++l) {
    gemm_xproj<<<dim3(G3_ / 64, (B_ * T_) / 64), 256, 0, stream>>>(
        in_seq, W + (size_t)l * D_ * G3_, bi + (size_t)l * G3_, xproj);
    if (l < L_ - 1) {
      scan2_kernel<true><<<B_, 768, 0, stream>>>(
          xproj, RTS + (size_t)l * RTS_L, br + (size_t)l * G3_, tokens,
          out_seq, nullptr);
    } else {
      scan2_kernel<false><<<B_, 768, 0, stream>>>(
          xproj, RTS + (size_t)l * RTS_L, br + (size_t)l * G3_, tokens,
          nullptr, hfinal);
    }
    const float* tmp = in_seq;
    in_seq = out_seq;
    out_seq = (float*)tmp;
  }
  fc_kernel<<<B_, 64, 0, stream>>>(hfinal, fcW, fcb, out);
}